// Round 13
// baseline (366.452 us; speedup 1.0000x reference)
//
#include <hip/hip_runtime.h>

// SchNet GNN, MI355X. fp16 datapath.
//  - W(d) table: NEAREST-NEIGHBOR, 4096 rows x 128ch fp16 = 1 MB/layer (same
//    L2 footprint as the proven lerp table; NN accuracy proven in r8 @8192).
//  - agg: lane covers 8 channels -> ONE 16B table load per edge per lane
//    (256B/edge-visit, half the lerp config's bytes+requests; no lerp VALU).
//  - r10-proven skeleton otherwise: ps in LDS, launch_bounds(256,4)
//    (VGPR>=64 needed for 8-deep ILP batch), h read inline in GEMM2.

#define NATOMS 32000
#define NPGC   1000
#define PSLOT  (NATOMS * 16)
#define LOG2F_ 0.69314718056f
#define TROWS  4096
#define DSC4   851.0f           // rows per Angstrom (4085 max at d=4.8)

typedef float f32x4 __attribute__((ext_vector_type(4)));
typedef _Float16 f16x8 __attribute__((ext_vector_type(8)));
typedef _Float16 h2 __attribute__((ext_vector_type(2)));

#define MFMA16H(a, b, c) __builtin_amdgcn_mfma_f32_16x16x32_f16(a, b, c, 0, 0, 0)

__device__ __forceinline__ unsigned short f2h(float f) {
  _Float16 h = (_Float16)f;
  return __builtin_bit_cast(unsigned short, h);
}
__device__ __forceinline__ h2 u2h2(unsigned int v) { return __builtin_bit_cast(h2, v); }
__device__ __forceinline__ unsigned int h22u(h2 v) { return __builtin_bit_cast(unsigned int, v); }
__device__ __forceinline__ float ssp(float v) {  // shifted softplus
  return fmaxf(v, 0.f) + __logf(1.f + __expf(-fabsf(v))) - LOG2F_;
}

// ================= merged setup: pair / prep / table / zero =================
// [0,2000): pairb  [2000,2018): weight swizzle  [2018,2402): tables  2402: sch
__global__ __launch_bounds__(256, 2) void setup_kernel(
    const float* __restrict__ pos, int* __restrict__ pairb,
    const float* __restrict__ lin1, const float* __restrict__ lin2,
    const float* __restrict__ lin, unsigned short* __restrict__ frag,
    const float* __restrict__ w1_, const float* __restrict__ b1_,
    const float* __restrict__ w2_, const float* __restrict__ b2_,
    unsigned short* __restrict__ tab16_, float* __restrict__ sch) {
  __shared__ unsigned short w1f[8192];
  __shared__ unsigned short w2f[16384];
  __shared__ unsigned short t1s[4][16 * 136];
  const int bid = blockIdx.x, tid = threadIdx.x;

  if (bid < 2000) {                          // ---- per-pair table row byte offset
    int p = bid * 256 + tid;
    int i = p >> 4, k = (p & 15) + 1;
    bool valid = (i % NPGC) + k < NPGC;
    int j = i + k; if (j >= NATOMS) j = NATOMS - 1;
    float dx = pos[3 * i] - pos[3 * j];
    float dy = pos[3 * i + 1] - pos[3 * j + 1];
    float dz = pos[3 * i + 2] - pos[3 * j + 2];
    float d = sqrtf(dx * dx + dy * dy + dz * dz);
    int idx;
    if (valid) {
      idx = (int)(d * DSC4 + 0.5f);
      if (idx > 4085) idx = 4085;
    } else {
      idx = 4092;                            // zero row
    }
    pairb[p] = idx << 8;                     // row stride 256 B
    return;
  }
  if (bid < 2018) {                          // ---- weight swizzle to B-frag layout
    int mat = bid - 2000;                    // 0..5 lin1, 6..11 lin2, 12..17 lin
    const float* w = mat < 6 ? lin1 + (size_t)mat * 16384
                   : mat < 12 ? lin2 + (size_t)(mat - 6) * 16384
                   : lin + (size_t)(mat - 12) * 16384;
    unsigned short* f = frag + (size_t)mat * 16384;
    for (int q = 0; q < 64; ++q) {
      int e = q * 256 + tid;
      int j = e & 7, lane = (e >> 3) & 63, tt = e >> 9;
      int n = tt >> 2, ks = tt & 3;
      int krow = ks * 32 + ((lane >> 4) << 3) + j;
      int col = (n << 4) + (lane & 15);
      f[e] = f2h(w[krow * 128 + col]);
    }
    return;
  }
  if (bid < 2402) {                          // ---- filter tables (MFMA, fp16 out)
    int t = bid - 2018;
    const int layer = t >> 6, bx = t & 63;   // 64 blocks x 64 rows = 4096 rows
    const float* w1 = w1_ + (size_t)layer * 50 * 128;
    const float* b1 = b1_ + (size_t)layer * 128;
    const float* w2 = w2_ + (size_t)layer * 128 * 128;
    const float* b2 = b2_ + (size_t)layer * 128;
    unsigned short* tab16 = tab16_ + (size_t)layer * TROWS * 128;

    for (int q = 0; q < 32; ++q) {
      int e = q * 256 + tid;
      int j = e & 7, lane = (e >> 3) & 63, tt = e >> 9;   // tt = n*2+ks
      int n = tt >> 1, ks = tt & 1;
      int krow = ks * 32 + ((lane >> 4) << 3) + j;
      int col = (n << 4) + (lane & 15);
      w1f[e] = f2h((krow < 50) ? w1[krow * 128 + col] : 0.f);
    }
    for (int q = 0; q < 64; ++q) {
      int e = q * 256 + tid;
      int j = e & 7, lane = (e >> 3) & 63, tt = e >> 9;   // tt = n*4+ks
      int n = tt >> 2, ks = tt & 3;
      int krow = ks * 32 + ((lane >> 4) << 3) + j;
      int col = (n << 4) + (lane & 15);
      w2f[e] = f2h(w2[krow * 128 + col]);
    }
    __syncthreads();

    const int lane = tid & 63, wv = tid >> 6;
    const int r = lane & 15, kg = lane >> 4;
    const int tile = bx * 4 + wv;            // 0..255
    float b1v[8], b2v[8];
    #pragma unroll
    for (int n = 0; n < 8; ++n) { b1v[n] = b1[(n << 4) + r]; b2v[n] = b2[(n << 4) + r]; }
    unsigned short* t1p = t1s[wv];

    const int p0 = tile << 4;
    const float step = 5.0f / 49.0f;
    const float coeff = -0.5f / (step * step);
    const float d = (float)(p0 + r) * (1.0f / DSC4);
    f16x8 a0, a1;
    #pragma unroll
    for (int j = 0; j < 8; ++j) {            // rbf(d) A-fragment, K padded to 64
      int g0 = (kg << 3) + j, g1 = g0 + 32;
      float t0 = d - step * g0, t1 = d - step * g1;
      a0[j] = (_Float16)((g0 < 50) ? __expf(coeff * t0 * t0) : 0.f);
      a1[j] = (_Float16)((g1 < 50) ? __expf(coeff * t1 * t1) : 0.f);
    }
    #pragma unroll
    for (int n = 0; n < 8; ++n) {            // GEMM1 (K=64) + ssp
      const f16x8 bA = *(const f16x8*)&w1f[(((n << 1)) * 64 + lane) << 3];
      const f16x8 bB = *(const f16x8*)&w1f[(((n << 1) | 1) * 64 + lane) << 3];
      f32x4 acc = {0.f, 0.f, 0.f, 0.f};
      acc = MFMA16H(a0, bA, acc);
      acc = MFMA16H(a1, bB, acc);
      #pragma unroll
      for (int j = 0; j < 4; ++j)
        t1p[((kg << 2) + j) * 136 + (n << 4) + r] = f2h(ssp(acc[j] + b1v[n]));
    }
    f16x8 a2[4];
    #pragma unroll
    for (int ks = 0; ks < 4; ++ks)
      a2[ks] = *(const f16x8*)&t1p[r * 136 + (ks << 5) + (kg << 3)];
    float cv[4];
    #pragma unroll
    for (int j = 0; j < 4; ++j) {
      float dj = (float)(p0 + (kg << 2) + j) * (1.0f / DSC4);
      cv[j] = 0.5f * (__cosf(dj * 0.62831853071795865f) + 1.0f);
    }
    #pragma unroll
    for (int n = 0; n < 8; ++n) {            // GEMM2 (K=128) + *C -> table
      f32x4 acc = {0.f, 0.f, 0.f, 0.f};
      #pragma unroll
      for (int ks = 0; ks < 4; ++ks)
        acc = MFMA16H(a2[ks], *(const f16x8*)&w2f[(((n << 2) | ks) * 64 + lane) << 3], acc);
      #pragma unroll
      for (int j = 0; j < 4; ++j) {
        int row = p0 + (kg << 2) + j;
        float val = (acc[j] + b2v[n]) * cv[j];
        if (row >= 4090) val = 0.f;          // zero rows for invalid pairs
        tab16[(size_t)row * 128 + (n << 4) + r] = f2h(val);
      }
    }
    return;
  }
  if (tid < 32) sch[tid] = 0.f;              // ---- zero graph sums
}

// ============ x0 = emb[z] @ lin1_0 (fp16) ; also writes h0 = emb[z] ============
__global__ __launch_bounds__(256, 2) void xgemm_kernel(
    const int* __restrict__ z, const float* __restrict__ emb,
    const unsigned short* __restrict__ frag,
    float* __restrict__ h, unsigned short* __restrict__ x) {
  const int tid = threadIdx.x, lane = tid & 63, wv = tid >> 6;
  const int wr = wv >> 1, wn = wv & 1;
  const int r = lane & 15, kg = lane >> 4;
  const int p0 = blockIdx.x * 32 + wr * 16;
  const float* hp = emb + (size_t)z[p0 + r] * 128 + (kg << 3);
  f16x8 a[4];
  #pragma unroll
  for (int ks = 0; ks < 4; ++ks) {
    float4 f0 = *(const float4*)(hp + (ks << 5));
    float4 f1 = *(const float4*)(hp + (ks << 5) + 4);
    f16x8 av;
    av[0] = (_Float16)f0.x; av[1] = (_Float16)f0.y;
    av[2] = (_Float16)f0.z; av[3] = (_Float16)f0.w;
    av[4] = (_Float16)f1.x; av[5] = (_Float16)f1.y;
    av[6] = (_Float16)f1.z; av[7] = (_Float16)f1.w;
    a[ks] = av;
    if (wn == 0) {                           // write h0 once
      *(float4*)&h[(size_t)(p0 + r) * 128 + (ks << 5) + (kg << 3)] = f0;
      *(float4*)&h[(size_t)(p0 + r) * 128 + (ks << 5) + (kg << 3) + 4] = f1;
    }
  }
  #pragma unroll
  for (int n = 0; n < 4; ++n) {
    int nn = (wn << 2) + n;
    f32x4 acc = {0.f, 0.f, 0.f, 0.f};
    #pragma unroll
    for (int ks = 0; ks < 4; ++ks)
      acc = MFMA16H(a[ks], *(const f16x8*)&frag[((((nn << 2) | ks) * 64 + lane) << 3)], acc);
    #pragma unroll
    for (int j = 0; j < 4; ++j)
      x[(size_t)(p0 + (kg << 2) + j) * 128 + (nn << 4) + r] = f2h(acc[j]);
  }
}

// ====== fused CFConv layer: NN-agg (8ch/lane) + 3 MFMA GEMMs, 32 atoms/block ======
template <int LAST>
__global__ __launch_bounds__(256, 4) void cfconv_kernel(
    const unsigned short* __restrict__ tab16,
    const int* __restrict__ pairb,
    const unsigned short* __restrict__ x,
    const unsigned short* __restrict__ w2f, const float* __restrict__ b2,
    const unsigned short* __restrict__ wlf, const float* __restrict__ bl,
    const unsigned short* __restrict__ w1nf,
    float* __restrict__ h, unsigned short* __restrict__ xout) {
  __shared__ unsigned short xs[64 * 128];    // 16 KB: x rows [base-16, base+48)
  __shared__ int ps[48 * 16];                // 3 KB: pair rows [base-16, base+32)
  __shared__ unsigned short t1s[32 * 136];   // 8.7 KB
  const int tid = threadIdx.x, lane = tid & 63, wv = tid >> 6;
  const int base = blockIdx.x * 32;
  #pragma unroll
  for (int q = 0; q < 4; ++q) {              // stage x halo
    int e = q * 256 + tid;
    int rr = e >> 4, c8 = e & 15;
    int src = base - 16 + rr;
    src = src < 0 ? 0 : (src >= NATOMS ? NATOMS - 1 : src);
    *(uint4*)&xs[rr * 128 + (c8 << 3)] = *(const uint4*)&x[(size_t)src * 128 + (c8 << 3)];
  }
  #pragma unroll
  for (int q = 0; q < 3; ++q) {              // stage pair rows
    int e = q * 256 + tid;
    int rr = e >> 4, kk = e & 15;
    int src = base - 16 + rr;
    src = src < 0 ? 0 : src;
    ps[e] = pairb[(size_t)src * 16 + kk];
  }
  __syncthreads();

  // ---- aggregation: lane = 8 channels x 4 atom-slots; 1x16B NN load/edge ----
  const int quarter = lane >> 4, cl = lane & 15;
  const int c = cl << 3;                     // 8-channel base
  const char* tbc = (const char*)tab16 + (c << 1);
  if (base > 0) {                            // fast path: no left-boundary guards
    for (int m = 0; m < 2; ++m) {
      const int ia = (wv << 3) + (quarter << 1) + m;
      const int li = ia + 16;
      const unsigned short* xrow = xs + li * 128 + c;
      const int* psr = ps + li * 16;
      h2 a01 = {(_Float16)0.f, (_Float16)0.f};
      h2 a23 = a01, a45 = a01, a67 = a01;
      #pragma unroll
      for (int chnk = 0; chnk < 2; ++chnk) { // RIGHT neighbors, k = chnk*8+1..+8
        int pr[8]; uint4 t[8]; uint4 xv[8];
        #pragma unroll
        for (int q = 0; q < 8; ++q) pr[q] = psr[chnk * 8 + q];
        #pragma unroll
        for (int q = 0; q < 8; ++q) {
          t[q] = *(const uint4*)(tbc + (unsigned)pr[q]);
          xv[q] = *(const uint4*)(xrow + ((chnk * 8 + q + 1) << 7));
        }
        #pragma unroll
        for (int q = 0; q < 8; ++q) {
          a01 += u2h2(t[q].x) * u2h2(xv[q].x);
          a23 += u2h2(t[q].y) * u2h2(xv[q].y);
          a45 += u2h2(t[q].z) * u2h2(xv[q].z);
          a67 += u2h2(t[q].w) * u2h2(xv[q].w);
        }
      }
      #pragma unroll
      for (int chnk = 0; chnk < 2; ++chnk) { // LEFT neighbors (mirror slots)
        int pr[8]; uint4 t[8]; uint4 xv[8];
        #pragma unroll
        for (int q = 0; q < 8; ++q) {
          int k = chnk * 8 + q + 1;
          pr[q] = ps[(li - k) * 16 + (k - 1)];
        }
        #pragma unroll
        for (int q = 0; q < 8; ++q) {
          t[q] = *(const uint4*)(tbc + (unsigned)pr[q]);
          xv[q] = *(const uint4*)(xrow - ((chnk * 8 + q + 1) << 7));
        }
        #pragma unroll
        for (int q = 0; q < 8; ++q) {
          a01 += u2h2(t[q].x) * u2h2(xv[q].x);
          a23 += u2h2(t[q].y) * u2h2(xv[q].y);
          a45 += u2h2(t[q].z) * u2h2(xv[q].z);
          a67 += u2h2(t[q].w) * u2h2(xv[q].w);
        }
      }
      uint4 o = {h22u(a01), h22u(a23), h22u(a45), h22u(a67)};
      *(uint4*)&t1s[ia * 136 + c] = o;       // 272B row stride: 16B-aligned
    }
  } else {                                   // block 0: guarded left edges
    for (int m = 0; m < 2; ++m) {
      const int ia = (wv << 3) + (quarter << 1) + m;
      const int i = base + ia;
      const int li = ia + 16;
      h2 a01 = {(_Float16)0.f, (_Float16)0.f};
      h2 a23 = a01, a45 = a01, a67 = a01;
      #pragma unroll
      for (int k = 1; k <= 16; ++k) {
        int pr = ps[li * 16 + k - 1];
        uint4 t = *(const uint4*)(tbc + (unsigned)pr);
        uint4 xv = *(const uint4*)&xs[(li + k) * 128 + c];
        a01 += u2h2(t.x) * u2h2(xv.x);
        a23 += u2h2(t.y) * u2h2(xv.y);
        a45 += u2h2(t.z) * u2h2(xv.z);
        a67 += u2h2(t.w) * u2h2(xv.w);
      }
      #pragma unroll
      for (int k = 1; k <= 16; ++k) {
        if (i - k >= 0) {
          int pr = ps[(li - k) * 16 + (k - 1)];
          uint4 t = *(const uint4*)(tbc + (unsigned)pr);
          uint4 xv = *(const uint4*)&xs[(li - k) * 128 + c];
          a01 += u2h2(t.x) * u2h2(xv.x);
          a23 += u2h2(t.y) * u2h2(xv.y);
          a45 += u2h2(t.z) * u2h2(xv.z);
          a67 += u2h2(t.w) * u2h2(xv.w);
        }
      }
      uint4 o = {h22u(a01), h22u(a23), h22u(a45), h22u(a67)};
      *(uint4*)&t1s[ia * 136 + c] = o;
    }
  }
  __syncthreads();

  // ---- GEMM phase: wave (wr,wn) owns 16-row half x 64-col half ----
  const int wr = wv >> 1, wn = wv & 1;
  const int r = lane & 15, kg = lane >> 4;
  const int p0 = base + wr * 16;
  const int p0l = wr * 16;
  float b2v[4], blv[4];
  #pragma unroll
  for (int n = 0; n < 4; ++n) {
    int cc = (((wn << 2) + n) << 4) + r;
    b2v[n] = b2[cc]; blv[n] = bl[cc];
  }
  f16x8 a[4];
  #pragma unroll
  for (int ks = 0; ks < 4; ++ks)
    a[ks] = *(const f16x8*)&t1s[(p0l + r) * 136 + (ks << 5) + (kg << 3)];
  __syncthreads();                           // agg reads done before t1 overwrite
  #pragma unroll
  for (int n = 0; n < 4; ++n) {              // GEMM1: agg@lin2 + b2, ssp -> t1
    int nn = (wn << 2) + n;
    f32x4 acc = {0.f, 0.f, 0.f, 0.f};
    #pragma unroll
    for (int ks = 0; ks < 4; ++ks)
      acc = MFMA16H(a[ks], *(const f16x8*)&w2f[((((nn << 2) | ks) * 64 + lane) << 3)], acc);
    #pragma unroll
    for (int j = 0; j < 4; ++j)
      t1s[(p0l + (kg << 2) + j) * 136 + (nn << 4) + r] = f2h(ssp(acc[j] + b2v[n]));
  }
  __syncthreads();
  f16x8 a2[4];
  #pragma unroll
  for (int ks = 0; ks < 4; ++ks)
    a2[ks] = *(const f16x8*)&t1s[(p0l + r) * 136 + (ks << 5) + (kg << 3)];
  float hn[4][4];
  #pragma unroll
  for (int n = 0; n < 4; ++n) {              // GEMM2: v@lin_w + bl + h -> h
    int nn = (wn << 2) + n;
    f32x4 acc = {0.f, 0.f, 0.f, 0.f};
    #pragma unroll
    for (int ks = 0; ks < 4; ++ks)
      acc = MFMA16H(a2[ks], *(const f16x8*)&wlf[((((nn << 2) | ks) * 64 + lane) << 3)], acc);
    #pragma unroll
    for (int j = 0; j < 4; ++j) {
      size_t off = (size_t)(p0 + (kg << 2) + j) * 128 + (nn << 4) + r;
      float val = h[off] + acc[j] + blv[n];
      h[off] = val;
      hn[n][j] = val;
    }
  }
  if constexpr (!LAST) {                     // GEMM3: x' = h_new @ lin1_next
    __syncthreads();                         // a2 reads done
    #pragma unroll
    for (int n = 0; n < 4; ++n)
      #pragma unroll
      for (int j = 0; j < 4; ++j)
        t1s[(p0l + (kg << 2) + j) * 136 + ((((wn << 2) + n)) << 4) + r] = f2h(hn[n][j]);
    __syncthreads();
    f16x8 a3[4];
    #pragma unroll
    for (int ks = 0; ks < 4; ++ks)
      a3[ks] = *(const f16x8*)&t1s[(p0l + r) * 136 + (ks << 5) + (kg << 3)];
    #pragma unroll
    for (int n = 0; n < 4; ++n) {
      int nn = (wn << 2) + n;
      f32x4 acc = {0.f, 0.f, 0.f, 0.f};
      #pragma unroll
      for (int ks = 0; ks < 4; ++ks)
        acc = MFMA16H(a3[ks], *(const f16x8*)&w1nf[((((nn << 2) | ks) * 64 + lane) << 3)], acc);
      #pragma unroll
      for (int j = 0; j < 4; ++j)
        xout[(size_t)(p0 + (kg << 2) + j) * 128 + (nn << 4) + r] = f2h(acc[j]);
    }
  }
}

// ---------------- output head ----------------
__global__ __launch_bounds__(256, 4) void head_atoms(const float* __restrict__ h,
    const float* __restrict__ o1w, const float* __restrict__ o1b,
    const float* __restrict__ o2w, const float* __restrict__ o2b,
    float* __restrict__ sch) {
  __shared__ float o1wT[64 * 132];
  __shared__ float hs[4][128];
  __shared__ float schloc[2];
  const int tid = threadIdx.x, lane = tid & 63, wv = tid >> 6;
  #pragma unroll
  for (int q = 0; q < 8; ++q) {
    int e4 = q * 256 + tid;
    int k = e4 >> 4, c0 = (e4 & 15) << 2;
    float4 v = ((const float4*)o1w)[e4];
    o1wT[(c0 + 0) * 132 + k] = v.x;
    o1wT[(c0 + 1) * 132 + k] = v.y;
    o1wT[(c0 + 2) * 132 + k] = v.z;
    o1wT[(c0 + 3) * 132 + k] = v.w;
  }
  if (tid < 2) schloc[tid] = 0.f;
  __syncthreads();
  const int base = blockIdx.x * 64;
  const int g0 = base / NPGC;
  const float o1bv = o1b[lane], o2wv = o2w[lane], o2bv = o2b[0];
  for (int m = 0; m < 16; ++m) {
    int i = base + (wv << 4) + m;
    __syncthreads();
    if (lane < 32) ((float4*)hs[wv])[lane] = ((const float4*)h)[(size_t)i * 32 + lane];
    __syncthreads();
    float4 acc = {0.f, 0.f, 0.f, 0.f};
    #pragma unroll
    for (int k4 = 0; k4 < 32; ++k4) {
      float4 wv4 = *(const float4*)&o1wT[lane * 132 + (k4 << 2)];
      float4 hb = ((const float4*)hs[wv])[k4];
      acc.x = fmaf(hb.x, wv4.x, acc.x);
      acc.y = fmaf(hb.y, wv4.y, acc.y);
      acc.z = fmaf(hb.z, wv4.z, acc.z);
      acc.w = fmaf(hb.w, wv4.w, acc.w);
    }
    float pa = ssp(acc.x + acc.y + acc.z + acc.w + o1bv) * o2wv;
    #pragma unroll
    for (int off = 32; off; off >>= 1) pa += __shfl_down(pa, off);
    if (lane == 0) atomicAdd(&schloc[(i / NPGC) - g0], pa + o2bv);
  }
  __syncthreads();
  if (tid < 2 && g0 + tid < 32) atomicAdd(&sch[g0 + tid], schloc[tid]);
}

__global__ void head_final(const float* __restrict__ sch,
    const float* __restrict__ h1w, const float* __restrict__ h1b,
    const float* __restrict__ h2w, const float* __restrict__ h2b,
    float* __restrict__ out) {
  int g = threadIdx.x;
  if (g < 32) {
    float s = sch[g], acc = h2b[0];
    for (int c = 0; c < 64; ++c) {
      float t = fmaf(s, h1w[c], h1b[c]);
      acc = fmaf(fmaxf(t, 0.f), h2w[c], acc);
    }
    out[g] = acc;
  }
}

extern "C" void kernel_launch(void* const* d_in, const int* in_sizes, int n_in,
                              void* d_out, int out_size, void* d_ws, size_t ws_size,
                              hipStream_t stream) {
  const int*   z       = (const int*)d_in[0];
  const float* pos     = (const float*)d_in[1];
  const float* emb     = (const float*)d_in[5];
  const float* mlp_w1  = (const float*)d_in[6];
  const float* mlp_b1  = (const float*)d_in[7];
  const float* mlp_w2  = (const float*)d_in[8];
  const float* mlp_b2  = (const float*)d_in[9];
  const float* lin1_w  = (const float*)d_in[10];
  const float* lin2_w  = (const float*)d_in[11];
  const float* lin2_b  = (const float*)d_in[12];
  const float* lin_w   = (const float*)d_in[13];
  const float* lin_b   = (const float*)d_in[14];
  const float* out1_w  = (const float*)d_in[15];
  const float* out1_b  = (const float*)d_in[16];
  const float* out2_w  = (const float*)d_in[17];
  const float* out2_b  = (const float*)d_in[18];
  const float* head1_w = (const float*)d_in[19];
  const float* head1_b = (const float*)d_in[20];
  const float* head2_w = (const float*)d_in[21];
  const float* head2_b = (const float*)d_in[22];
  float* outp = (float*)d_out;

  char* ws = (char*)d_ws;
  const size_t SZ_NODE = (size_t)NATOMS * 128 * 4;  // 16.384 MB
  float* h    = (float*)ws;                   ws += SZ_NODE;
  unsigned short* xA   = (unsigned short*)ws; ws += SZ_NODE / 2;   // fp16
  unsigned short* xB   = (unsigned short*)ws; ws += SZ_NODE / 2;   // fp16
  int* pairb = (int*)ws;                      ws += (size_t)PSLOT * 4;
  unsigned short* tab16 = (unsigned short*)ws; ws += (size_t)6 * TROWS * 256;
  unsigned short* frag = (unsigned short*)ws; ws += (size_t)18 * 16384 * 2;
  float* sch  = (float*)ws;                   ws += 256;
  if ((size_t)(ws - (char*)d_ws) > ws_size) return;

  const unsigned short* f_lin1 = frag;
  const unsigned short* f_lin2 = frag + (size_t)6 * 16384;
  const unsigned short* f_lin  = frag + (size_t)12 * 16384;

  setup_kernel<<<2403, 256, 0, stream>>>(pos, pairb, lin1_w, lin2_w, lin_w, frag,
                                         mlp_w1, mlp_b1, mlp_w2, mlp_b2, tab16, sch);
  xgemm_kernel<<<NATOMS / 32, 256, 0, stream>>>(z, emb, f_lin1, h, xA);

  for (int l = 0; l < 6; ++l) {
    unsigned short* xin  = (l & 1) ? xB : xA;
    unsigned short* xo   = (l & 1) ? xA : xB;
    if (l < 5)
      cfconv_kernel<0><<<NATOMS / 32, 256, 0, stream>>>(
          tab16 + (size_t)l * TROWS * 128, pairb, xin,
          f_lin2 + (size_t)l * 16384, lin2_b + (size_t)l * 128,
          f_lin + (size_t)l * 16384, lin_b + (size_t)l * 128,
          f_lin1 + (size_t)(l + 1) * 16384, h, xo);
    else
      cfconv_kernel<1><<<NATOMS / 32, 256, 0, stream>>>(
          tab16 + (size_t)l * TROWS * 128, pairb, xin,
          f_lin2 + (size_t)l * 16384, lin2_b + (size_t)l * 128,
          f_lin + (size_t)l * 16384, lin_b + (size_t)l * 128,
          f_lin1, h, xo);
  }
  head_atoms<<<NATOMS / 64, 256, 0, stream>>>(h, out1_w, out1_b, out2_w, out2_b, sch);
  head_final<<<1, 64, 0, stream>>>(sch, head1_w, head1_b, head2_w, head2_b, outp);
}

// Round 14
// 283.397 us; speedup vs baseline: 1.2931x; 1.2931x over previous
//
#include <hip/hip_runtime.h>

// SchNet GNN, MI355X. fp16 datapath, lerp filter table — EXACT r10 structure
// (proven 275.7 us twice; r8/r11/r13 deviations all regressed 20-90 us).
// Single change this round: XCD-aware blockIdx swizzle on cfconv so
// neighboring atom-blocks (shared x-halo rows + locally-correlated table
// rows) land on the same XCD's L2. Bijective: 1000 blocks % 8 == 0.

#define NATOMS 32000
#define NPGC   1000
#define PSLOT  (NATOMS * 16)
#define LOG2F_ 0.69314718056f
#define TROWS  2048
#define DSCALE 425.0f           // 2040 / 4.8

typedef float f32x4 __attribute__((ext_vector_type(4)));
typedef _Float16 f16x8 __attribute__((ext_vector_type(8)));
typedef _Float16 h2 __attribute__((ext_vector_type(2)));

#define MFMA16H(a, b, c) __builtin_amdgcn_mfma_f32_16x16x32_f16(a, b, c, 0, 0, 0)

__device__ __forceinline__ unsigned short f2h(float f) {
  _Float16 h = (_Float16)f;
  return __builtin_bit_cast(unsigned short, h);
}
__device__ __forceinline__ h2 u2h2(unsigned int v) { return __builtin_bit_cast(h2, v); }
__device__ __forceinline__ unsigned int h22u(h2 v) { return __builtin_bit_cast(unsigned int, v); }
__device__ __forceinline__ float ssp(float v) {  // shifted softplus
  return fmaxf(v, 0.f) + __logf(1.f + __expf(-fabsf(v))) - LOG2F_;
}

// ================= merged setup: pair / prep / table / zero =================
__global__ __launch_bounds__(256, 2) void setup_kernel(
    const float* __restrict__ pos, int2* __restrict__ pairb,
    const float* __restrict__ lin1, const float* __restrict__ lin2,
    const float* __restrict__ lin, unsigned short* __restrict__ frag,
    const float* __restrict__ w1_, const float* __restrict__ b1_,
    const float* __restrict__ w2_, const float* __restrict__ b2_,
    unsigned short* __restrict__ tab16_, float* __restrict__ sch) {
  __shared__ unsigned short w1f[8192];
  __shared__ unsigned short w2f[16384];
  __shared__ unsigned short t1s[4][16 * 136];
  const int bid = blockIdx.x, tid = threadIdx.x;

  if (bid < 2000) {                          // ---- per-pair {byte off, frac fp16x2}
    int p = bid * 256 + tid;
    int i = p >> 4, k = (p & 15) + 1;
    bool valid = (i % NPGC) + k < NPGC;
    int j = i + k; if (j >= NATOMS) j = NATOMS - 1;
    float dx = pos[3 * i] - pos[3 * j];
    float dy = pos[3 * i + 1] - pos[3 * j + 1];
    float dz = pos[3 * i + 2] - pos[3 * j + 2];
    float d = sqrtf(dx * dx + dy * dy + dz * dz);
    int2 pv;
    if (valid) {
      float uu = fminf(d * DSCALE, 2044.0f);
      int idx = (int)uu;
      _Float16 fh = (_Float16)(uu - (float)idx);
      h2 fp = {fh, fh};
      pv.x = idx * 512;                      // row stride 512 B
      pv.y = (int)h22u(fp);
    } else {
      pv.x = 2046 * 512;                     // zero row
      pv.y = 0;
    }
    pairb[p] = pv;
    return;
  }
  if (bid < 2018) {                          // ---- weight swizzle to B-frag layout
    int mat = bid - 2000;                    // 0..5 lin1, 6..11 lin2, 12..17 lin
    const float* w = mat < 6 ? lin1 + (size_t)mat * 16384
                   : mat < 12 ? lin2 + (size_t)(mat - 6) * 16384
                   : lin + (size_t)(mat - 12) * 16384;
    unsigned short* f = frag + (size_t)mat * 16384;
    for (int q = 0; q < 64; ++q) {
      int e = q * 256 + tid;
      int j = e & 7, lane = (e >> 3) & 63, tt = e >> 9;
      int n = tt >> 2, ks = tt & 3;
      int krow = ks * 32 + ((lane >> 4) << 3) + j;
      int col = (n << 4) + (lane & 15);
      f[e] = f2h(w[krow * 128 + col]);
    }
    return;
  }
  if (bid < 2210) {                          // ---- filter tables (MFMA, fp16 out)
    int t = bid - 2018;
    const int layer = t >> 5, bx = t & 31;
    const float* w1 = w1_ + (size_t)layer * 50 * 128;
    const float* b1 = b1_ + (size_t)layer * 128;
    const float* w2 = w2_ + (size_t)layer * 128 * 128;
    const float* b2 = b2_ + (size_t)layer * 128;
    unsigned short* tab16 = tab16_ + (size_t)layer * TROWS * 256;

    for (int q = 0; q < 32; ++q) {
      int e = q * 256 + tid;
      int j = e & 7, lane = (e >> 3) & 63, tt = e >> 9;   // tt = n*2+ks
      int n = tt >> 1, ks = tt & 1;
      int krow = ks * 32 + ((lane >> 4) << 3) + j;
      int col = (n << 4) + (lane & 15);
      w1f[e] = f2h((krow < 50) ? w1[krow * 128 + col] : 0.f);
    }
    for (int q = 0; q < 64; ++q) {
      int e = q * 256 + tid;
      int j = e & 7, lane = (e >> 3) & 63, tt = e >> 9;   // tt = n*4+ks
      int n = tt >> 2, ks = tt & 3;
      int krow = ks * 32 + ((lane >> 4) << 3) + j;
      int col = (n << 4) + (lane & 15);
      w2f[e] = f2h(w2[krow * 128 + col]);
    }
    __syncthreads();

    const int lane = tid & 63, wv = tid >> 6;
    const int r = lane & 15, kg = lane >> 4;
    const int tile = bx * 4 + wv;            // 0..127
    float b1v[8], b2v[8];
    #pragma unroll
    for (int n = 0; n < 8; ++n) { b1v[n] = b1[(n << 4) + r]; b2v[n] = b2[(n << 4) + r]; }
    unsigned short* t1p = t1s[wv];

    const int p0 = tile << 4;
    const float step = 5.0f / 49.0f;
    const float coeff = -0.5f / (step * step);
    const float d = (float)(p0 + r) * (1.0f / DSCALE);
    f16x8 a0, a1;
    #pragma unroll
    for (int j = 0; j < 8; ++j) {            // rbf(d) A-fragment, K padded to 64
      int g0 = (kg << 3) + j, g1 = g0 + 32;
      float t0 = d - step * g0, t1 = d - step * g1;
      a0[j] = (_Float16)((g0 < 50) ? __expf(coeff * t0 * t0) : 0.f);
      a1[j] = (_Float16)((g1 < 50) ? __expf(coeff * t1 * t1) : 0.f);
    }
    #pragma unroll
    for (int n = 0; n < 8; ++n) {            // GEMM1 (K=64) + ssp
      const f16x8 bA = *(const f16x8*)&w1f[(((n << 1)) * 64 + lane) << 3];
      const f16x8 bB = *(const f16x8*)&w1f[(((n << 1) | 1) * 64 + lane) << 3];
      f32x4 acc = {0.f, 0.f, 0.f, 0.f};
      acc = MFMA16H(a0, bA, acc);
      acc = MFMA16H(a1, bB, acc);
      #pragma unroll
      for (int j = 0; j < 4; ++j)
        t1p[((kg << 2) + j) * 136 + (n << 4) + r] = f2h(ssp(acc[j] + b1v[n]));
    }
    f16x8 a2[4];
    #pragma unroll
    for (int ks = 0; ks < 4; ++ks)
      a2[ks] = *(const f16x8*)&t1p[r * 136 + (ks << 5) + (kg << 3)];
    float cv[4];
    #pragma unroll
    for (int j = 0; j < 4; ++j) {
      float dj = (float)(p0 + (kg << 2) + j) * (1.0f / DSCALE);
      cv[j] = 0.5f * (__cosf(dj * 0.62831853071795865f) + 1.0f);
    }
    #pragma unroll
    for (int n = 0; n < 8; ++n) {            // GEMM2 (K=128) + *C -> interleaved table
      f32x4 acc = {0.f, 0.f, 0.f, 0.f};
      #pragma unroll
      for (int ks = 0; ks < 4; ++ks)
        acc = MFMA16H(a2[ks], *(const f16x8*)&w2f[(((n << 2) | ks) * 64 + lane) << 3], acc);
      #pragma unroll
      for (int j = 0; j < 4; ++j) {
        int row = p0 + (kg << 2) + j;
        int ch = (n << 4) + r;
        float val = (acc[j] + b2v[n]) * cv[j];
        if (row >= TROWS - 2) val = 0.f;     // zero rows for invalid pairs
        unsigned short hv = f2h(val);
        size_t rb = (size_t)row * 256 + ((ch >> 1) << 2) + (ch & 1);
        tab16[rb] = hv;                      // lo slot of row
        if (row > 0) tab16[rb - 256 + 2] = hv;  // hi slot of row-1
      }
    }
    return;
  }
  if (tid < 32) sch[tid] = 0.f;              // ---- zero graph sums
}

// ============ x0 = emb[z] @ lin1_0 (fp16) ; also writes h0 = emb[z] ============
__global__ __launch_bounds__(256, 2) void xgemm_kernel(
    const int* __restrict__ z, const float* __restrict__ emb,
    const unsigned short* __restrict__ frag,
    float* __restrict__ h, unsigned short* __restrict__ x) {
  const int tid = threadIdx.x, lane = tid & 63, wv = tid >> 6;
  const int wr = wv >> 1, wn = wv & 1;
  const int r = lane & 15, kg = lane >> 4;
  const int p0 = blockIdx.x * 32 + wr * 16;
  const float* hp = emb + (size_t)z[p0 + r] * 128 + (kg << 3);
  f16x8 a[4];
  #pragma unroll
  for (int ks = 0; ks < 4; ++ks) {
    float4 f0 = *(const float4*)(hp + (ks << 5));
    float4 f1 = *(const float4*)(hp + (ks << 5) + 4);
    f16x8 av;
    av[0] = (_Float16)f0.x; av[1] = (_Float16)f0.y;
    av[2] = (_Float16)f0.z; av[3] = (_Float16)f0.w;
    av[4] = (_Float16)f1.x; av[5] = (_Float16)f1.y;
    av[6] = (_Float16)f1.z; av[7] = (_Float16)f1.w;
    a[ks] = av;
    if (wn == 0) {                           // write h0 once
      *(float4*)&h[(size_t)(p0 + r) * 128 + (ks << 5) + (kg << 3)] = f0;
      *(float4*)&h[(size_t)(p0 + r) * 128 + (ks << 5) + (kg << 3) + 4] = f1;
    }
  }
  #pragma unroll
  for (int n = 0; n < 4; ++n) {
    int nn = (wn << 2) + n;
    f32x4 acc = {0.f, 0.f, 0.f, 0.f};
    #pragma unroll
    for (int ks = 0; ks < 4; ++ks)
      acc = MFMA16H(a[ks], *(const f16x8*)&frag[((((nn << 2) | ks) * 64 + lane) << 3)], acc);
    #pragma unroll
    for (int j = 0; j < 4; ++j)
      x[(size_t)(p0 + (kg << 2) + j) * 128 + (nn << 4) + r] = f2h(acc[j]);
  }
}

// ====== fused CFConv layer: pipelined agg + 3 MFMA GEMMs, 32 atoms/block ======
// r10-proven structure; XCD swizzle: bid = (b%8)*125 + b/8 (bijective, 1000%8==0)
template <int LAST>
__global__ __launch_bounds__(256, 4) void cfconv_kernel(
    const unsigned short* __restrict__ tab16,
    const int2* __restrict__ pairb,
    const unsigned short* __restrict__ x,
    const unsigned short* __restrict__ w2f, const float* __restrict__ b2,
    const unsigned short* __restrict__ wlf, const float* __restrict__ bl,
    const unsigned short* __restrict__ w1nf,
    float* __restrict__ h, unsigned short* __restrict__ xout) {
  __shared__ unsigned short xs[64 * 128];    // 16 KB: x rows [base-16, base+48)
  __shared__ int2 ps[48 * 16];               // 6 KB: pair rows [base-16, base+32)
  __shared__ unsigned short t1s[32 * 136];   // 8.7 KB
  const int tid = threadIdx.x, lane = tid & 63, wv = tid >> 6;
  const int bid = (blockIdx.x & 7) * 125 + (blockIdx.x >> 3);  // XCD-contiguous
  const int base = bid * 32;
  #pragma unroll
  for (int q = 0; q < 4; ++q) {              // stage x halo
    int e = q * 256 + tid;
    int rr = e >> 4, c8 = e & 15;
    int src = base - 16 + rr;
    src = src < 0 ? 0 : (src >= NATOMS ? NATOMS - 1 : src);
    *(uint4*)&xs[rr * 128 + (c8 << 3)] = *(const uint4*)&x[(size_t)src * 128 + (c8 << 3)];
  }
  #pragma unroll
  for (int q = 0; q < 3; ++q) {              // stage pair rows
    int e = q * 256 + tid;
    int rr = e >> 4, kk = e & 15;
    int src = base - 16 + rr;
    src = src < 0 ? 0 : src;
    ps[e] = pairb[(size_t)src * 16 + kk];
  }
  __syncthreads();

  // ---- aggregation: thread = 4 atoms x 4 channels; 8 table loads in flight ----
  const int half = lane >> 5, cgi = lane & 31;
  const int c = cgi << 2;
  const char* tbc = (const char*)tab16 + (c << 2);
  if (base > 0) {                            // fast path: no left-boundary guards
    for (int m = 0; m < 4; ++m) {
      const int ia = (wv << 3) + (half << 2) + m;
      const int li = ia + 16;
      const unsigned short* xrow = xs + li * 128 + c;
      const int2* psr = ps + li * 16;
      h2 acc01 = {(_Float16)0.f, (_Float16)0.f};
      h2 acc23 = acc01;
      #pragma unroll
      for (int chnk = 0; chnk < 2; ++chnk) { // RIGHT neighbors, k = chnk*8+1..+8
        int2 pr[8];
        #pragma unroll
        for (int q = 0; q < 8; ++q) pr[q] = psr[chnk * 8 + q];
        uint4 t[8]; uint2 xv[8];
        #pragma unroll
        for (int q = 0; q < 8; ++q) {
          t[q] = *(const uint4*)(tbc + (unsigned)pr[q].x);
          xv[q] = *(const uint2*)(xrow + ((chnk * 8 + q + 1) << 7));
        }
        #pragma unroll
        for (int q = 0; q < 8; ++q) {
          h2 fr = u2h2((unsigned)pr[q].y);
          h2 lo01 = u2h2(t[q].x), hi01 = u2h2(t[q].y);
          h2 lo23 = u2h2(t[q].z), hi23 = u2h2(t[q].w);
          acc01 += (lo01 + fr * (hi01 - lo01)) * u2h2(xv[q].x);
          acc23 += (lo23 + fr * (hi23 - lo23)) * u2h2(xv[q].y);
        }
      }
      #pragma unroll
      for (int chnk = 0; chnk < 2; ++chnk) { // LEFT neighbors (mirror slots)
        int2 pr[8];
        #pragma unroll
        for (int q = 0; q < 8; ++q) {
          int k = chnk * 8 + q + 1;
          pr[q] = ps[(li - k) * 16 + (k - 1)];
        }
        uint4 t[8]; uint2 xv[8];
        #pragma unroll
        for (int q = 0; q < 8; ++q) {
          t[q] = *(const uint4*)(tbc + (unsigned)pr[q].x);
          xv[q] = *(const uint2*)(xrow - ((chnk * 8 + q + 1) << 7));
        }
        #pragma unroll
        for (int q = 0; q < 8; ++q) {
          h2 fr = u2h2((unsigned)pr[q].y);
          h2 lo01 = u2h2(t[q].x), hi01 = u2h2(t[q].y);
          h2 lo23 = u2h2(t[q].z), hi23 = u2h2(t[q].w);
          acc01 += (lo01 + fr * (hi01 - lo01)) * u2h2(xv[q].x);
          acc23 += (lo23 + fr * (hi23 - lo23)) * u2h2(xv[q].y);
        }
      }
      uint2 o = {h22u(acc01), h22u(acc23)};
      *(uint2*)&t1s[ia * 136 + c] = o;
    }
  } else {                                   // block 0: guarded left edges
    for (int m = 0; m < 4; ++m) {
      const int ia = (wv << 3) + (half << 2) + m;
      const int i = base + ia;
      const int li = ia + 16;
      h2 acc01 = {(_Float16)0.f, (_Float16)0.f};
      h2 acc23 = acc01;
      #pragma unroll
      for (int k = 1; k <= 16; ++k) {
        int2 pr = ps[li * 16 + k - 1];
        h2 fr = u2h2((unsigned)pr.y);
        uint4 t = *(const uint4*)(tbc + (unsigned)pr.x);
        uint2 xv = *(const uint2*)&xs[(li + k) * 128 + c];
        h2 lo01 = u2h2(t.x), hi01 = u2h2(t.y), lo23 = u2h2(t.z), hi23 = u2h2(t.w);
        acc01 += (lo01 + fr * (hi01 - lo01)) * u2h2(xv.x);
        acc23 += (lo23 + fr * (hi23 - lo23)) * u2h2(xv.y);
      }
      #pragma unroll
      for (int k = 1; k <= 16; ++k) {
        if (i - k >= 0) {
          int2 pr = ps[(li - k) * 16 + (k - 1)];
          h2 fr = u2h2((unsigned)pr.y);
          uint4 t = *(const uint4*)(tbc + (unsigned)pr.x);
          uint2 xv = *(const uint2*)&xs[(li - k) * 128 + c];
          h2 lo01 = u2h2(t.x), hi01 = u2h2(t.y), lo23 = u2h2(t.z), hi23 = u2h2(t.w);
          acc01 += (lo01 + fr * (hi01 - lo01)) * u2h2(xv.x);
          acc23 += (lo23 + fr * (hi23 - lo23)) * u2h2(xv.y);
        }
      }
      uint2 o = {h22u(acc01), h22u(acc23)};
      *(uint2*)&t1s[ia * 136 + c] = o;
    }
  }
  __syncthreads();

  // ---- GEMM phase: wave (wr,wn) owns 16-row half x 64-col half ----
  const int wr = wv >> 1, wn = wv & 1;
  const int r = lane & 15, kg = lane >> 4;
  const int p0 = base + wr * 16;
  const int p0l = wr * 16;
  float b2v[4], blv[4];
  #pragma unroll
  for (int n = 0; n < 4; ++n) {
    int cc = (((wn << 2) + n) << 4) + r;
    b2v[n] = b2[cc]; blv[n] = bl[cc];
  }
  f16x8 a[4];
  #pragma unroll
  for (int ks = 0; ks < 4; ++ks)
    a[ks] = *(const f16x8*)&t1s[(p0l + r) * 136 + (ks << 5) + (kg << 3)];
  __syncthreads();                           // agg reads done before t1 overwrite
  #pragma unroll
  for (int n = 0; n < 4; ++n) {              // GEMM1: agg@lin2 + b2, ssp -> t1
    int nn = (wn << 2) + n;
    f32x4 acc = {0.f, 0.f, 0.f, 0.f};
    #pragma unroll
    for (int ks = 0; ks < 4; ++ks)
      acc = MFMA16H(a[ks], *(const f16x8*)&w2f[((((nn << 2) | ks) * 64 + lane) << 3)], acc);
    #pragma unroll
    for (int j = 0; j < 4; ++j)
      t1s[(p0l + (kg << 2) + j) * 136 + (nn << 4) + r] = f2h(ssp(acc[j] + b2v[n]));
  }
  __syncthreads();
  f16x8 a2[4];
  #pragma unroll
  for (int ks = 0; ks < 4; ++ks)
    a2[ks] = *(const f16x8*)&t1s[(p0l + r) * 136 + (ks << 5) + (kg << 3)];
  float hn[4][4];
  #pragma unroll
  for (int n = 0; n < 4; ++n) {              // GEMM2: v@lin_w + bl + h -> h
    int nn = (wn << 2) + n;
    f32x4 acc = {0.f, 0.f, 0.f, 0.f};
    #pragma unroll
    for (int ks = 0; ks < 4; ++ks)
      acc = MFMA16H(a2[ks], *(const f16x8*)&wlf[((((nn << 2) | ks) * 64 + lane) << 3)], acc);
    #pragma unroll
    for (int j = 0; j < 4; ++j) {
      size_t off = (size_t)(p0 + (kg << 2) + j) * 128 + (nn << 4) + r;
      float val = h[off] + acc[j] + blv[n];
      h[off] = val;
      hn[n][j] = val;
    }
  }
  if constexpr (!LAST) {                     // GEMM3: x' = h_new @ lin1_next
    __syncthreads();                         // a2 reads done
    #pragma unroll
    for (int n = 0; n < 4; ++n)
      #pragma unroll
      for (int j = 0; j < 4; ++j)
        t1s[(p0l + (kg << 2) + j) * 136 + ((((wn << 2) + n)) << 4) + r] = f2h(hn[n][j]);
    __syncthreads();
    f16x8 a3[4];
    #pragma unroll
    for (int ks = 0; ks < 4; ++ks)
      a3[ks] = *(const f16x8*)&t1s[(p0l + r) * 136 + (ks << 5) + (kg << 3)];
    #pragma unroll
    for (int n = 0; n < 4; ++n) {
      int nn = (wn << 2) + n;
      f32x4 acc = {0.f, 0.f, 0.f, 0.f};
      #pragma unroll
      for (int ks = 0; ks < 4; ++ks)
        acc = MFMA16H(a3[ks], *(const f16x8*)&w1nf[((((nn << 2) | ks) * 64 + lane) << 3)], acc);
      #pragma unroll
      for (int j = 0; j < 4; ++j)
        xout[(size_t)(p0 + (kg << 2) + j) * 128 + (nn << 4) + r] = f2h(acc[j]);
    }
  }
}

// ---------------- output head ----------------
__global__ __launch_bounds__(256, 4) void head_atoms(const float* __restrict__ h,
    const float* __restrict__ o1w, const float* __restrict__ o1b,
    const float* __restrict__ o2w, const float* __restrict__ o2b,
    float* __restrict__ sch) {
  __shared__ float o1wT[64 * 132];
  __shared__ float hs[4][128];
  __shared__ float schloc[2];
  const int tid = threadIdx.x, lane = tid & 63, wv = tid >> 6;
  #pragma unroll
  for (int q = 0; q < 8; ++q) {
    int e4 = q * 256 + tid;
    int k = e4 >> 4, c0 = (e4 & 15) << 2;
    float4 v = ((const float4*)o1w)[e4];
    o1wT[(c0 + 0) * 132 + k] = v.x;
    o1wT[(c0 + 1) * 132 + k] = v.y;
    o1wT[(c0 + 2) * 132 + k] = v.z;
    o1wT[(c0 + 3) * 132 + k] = v.w;
  }
  if (tid < 2) schloc[tid] = 0.f;
  __syncthreads();
  const int base = blockIdx.x * 64;
  const int g0 = base / NPGC;
  const float o1bv = o1b[lane], o2wv = o2w[lane], o2bv = o2b[0];
  for (int m = 0; m < 16; ++m) {
    int i = base + (wv << 4) + m;
    __syncthreads();
    if (lane < 32) ((float4*)hs[wv])[lane] = ((const float4*)h)[(size_t)i * 32 + lane];
    __syncthreads();
    float4 acc = {0.f, 0.f, 0.f, 0.f};
    #pragma unroll
    for (int k4 = 0; k4 < 32; ++k4) {
      float4 wv4 = *(const float4*)&o1wT[lane * 132 + (k4 << 2)];
      float4 hb = ((const float4*)hs[wv])[k4];
      acc.x = fmaf(hb.x, wv4.x, acc.x);
      acc.y = fmaf(hb.y, wv4.y, acc.y);
      acc.z = fmaf(hb.z, wv4.z, acc.z);
      acc.w = fmaf(hb.w, wv4.w, acc.w);
    }
    float pa = ssp(acc.x + acc.y + acc.z + acc.w + o1bv) * o2wv;
    #pragma unroll
    for (int off = 32; off; off >>= 1) pa += __shfl_down(pa, off);
    if (lane == 0) atomicAdd(&schloc[(i / NPGC) - g0], pa + o2bv);
  }
  __syncthreads();
  if (tid < 2 && g0 + tid < 32) atomicAdd(&sch[g0 + tid], schloc[tid]);
}

__global__ void head_final(const float* __restrict__ sch,
    const float* __restrict__ h1w, const float* __restrict__ h1b,
    const float* __restrict__ h2w, const float* __restrict__ h2b,
    float* __restrict__ out) {
  int g = threadIdx.x;
  if (g < 32) {
    float s = sch[g], acc = h2b[0];
    for (int c = 0; c < 64; ++c) {
      float t = fmaf(s, h1w[c], h1b[c]);
      acc = fmaf(fmaxf(t, 0.f), h2w[c], acc);
    }
    out[g] = acc;
  }
}

extern "C" void kernel_launch(void* const* d_in, const int* in_sizes, int n_in,
                              void* d_out, int out_size, void* d_ws, size_t ws_size,
                              hipStream_t stream) {
  const int*   z       = (const int*)d_in[0];
  const float* pos     = (const float*)d_in[1];
  const float* emb     = (const float*)d_in[5];
  const float* mlp_w1  = (const float*)d_in[6];
  const float* mlp_b1  = (const float*)d_in[7];
  const float* mlp_w2  = (const float*)d_in[8];
  const float* mlp_b2  = (const float*)d_in[9];
  const float* lin1_w  = (const float*)d_in[10];
  const float* lin2_w  = (const float*)d_in[11];
  const float* lin2_b  = (const float*)d_in[12];
  const float* lin_w   = (const float*)d_in[13];
  const float* lin_b   = (const float*)d_in[14];
  const float* out1_w  = (const float*)d_in[15];
  const float* out1_b  = (const float*)d_in[16];
  const float* out2_w  = (const float*)d_in[17];
  const float* out2_b  = (const float*)d_in[18];
  const float* head1_w = (const float*)d_in[19];
  const float* head1_b = (const float*)d_in[20];
  const float* head2_w = (const float*)d_in[21];
  const float* head2_b = (const float*)d_in[22];
  float* outp = (float*)d_out;

  char* ws = (char*)d_ws;
  const size_t SZ_NODE = (size_t)NATOMS * 128 * 4;  // 16.384 MB
  float* h    = (float*)ws;                   ws += SZ_NODE;
  unsigned short* xA   = (unsigned short*)ws; ws += SZ_NODE / 2;   // fp16
  unsigned short* xB   = (unsigned short*)ws; ws += SZ_NODE / 2;   // fp16
  int2* pairb = (int2*)ws;                    ws += (size_t)PSLOT * 8;
  unsigned short* tab16 = (unsigned short*)ws; ws += (size_t)6 * TROWS * 512;
  unsigned short* frag = (unsigned short*)ws; ws += (size_t)18 * 16384 * 2;
  float* sch  = (float*)ws;                   ws += 256;
  if ((size_t)(ws - (char*)d_ws) > ws_size) return;

  const unsigned short* f_lin1 = frag;
  const unsigned short* f_lin2 = frag + (size_t)6 * 16384;
  const unsigned short* f_lin  = frag + (size_t)12 * 16384;

  setup_kernel<<<2211, 256, 0, stream>>>(pos, pairb, lin1_w, lin2_w, lin_w, frag,
                                         mlp_w1, mlp_b1, mlp_w2, mlp_b2, tab16, sch);
  xgemm_kernel<<<NATOMS / 32, 256, 0, stream>>>(z, emb, f_lin1, h, xA);

  for (int l = 0; l < 6; ++l) {
    unsigned short* xin  = (l & 1) ? xB : xA;
    unsigned short* xo   = (l & 1) ? xA : xB;
    if (l < 5)
      cfconv_kernel<0><<<NATOMS / 32, 256, 0, stream>>>(
          tab16 + (size_t)l * TROWS * 256, pairb, xin,
          f_lin2 + (size_t)l * 16384, lin2_b + (size_t)l * 128,
          f_lin + (size_t)l * 16384, lin_b + (size_t)l * 128,
          f_lin1 + (size_t)(l + 1) * 16384, h, xo);
    else
      cfconv_kernel<1><<<NATOMS / 32, 256, 0, stream>>>(
          tab16 + (size_t)l * TROWS * 256, pairb, xin,
          f_lin2 + (size_t)l * 16384, lin2_b + (size_t)l * 128,
          f_lin + (size_t)l * 16384, lin_b + (size_t)l * 128,
          f_lin1, h, xo);
  }
  head_atoms<<<NATOMS / 64, 256, 0, stream>>>(h, out1_w, out1_b, out2_w, out2_b, sch);
  head_final<<<1, 64, 0, stream>>>(sch, head1_w, head1_b, head2_w, head2_b, outp);
}

// Round 15
// 275.332 us; speedup vs baseline: 1.3309x; 1.0293x over previous
//
#include <hip/hip_runtime.h>

// SchNet GNN, MI355X. fp16 datapath, lerp filter table — EXACT r7/r10 config,
// the measured local optimum (275.7 us, reproduced twice). Six orthogonal
// deviations all regressed: NN-table (r8/r13, L2 thrash), cooperative
// mega-kernel (r9/r10, grid.sync ~150us x8), occupancy-6 (r11, VGPR 40 kills
// 8-deep ILP), h-prefetch (r12, agg register pressure), XCD swizzle (r14,
// L3-fit so only dispatch perturbation). Do not deviate without new evidence.

#define NATOMS 32000
#define NPGC   1000
#define PSLOT  (NATOMS * 16)
#define LOG2F_ 0.69314718056f
#define TROWS  2048
#define DSCALE 425.0f           // 2040 / 4.8

typedef float f32x4 __attribute__((ext_vector_type(4)));
typedef _Float16 f16x8 __attribute__((ext_vector_type(8)));
typedef _Float16 h2 __attribute__((ext_vector_type(2)));

#define MFMA16H(a, b, c) __builtin_amdgcn_mfma_f32_16x16x32_f16(a, b, c, 0, 0, 0)

__device__ __forceinline__ unsigned short f2h(float f) {
  _Float16 h = (_Float16)f;
  return __builtin_bit_cast(unsigned short, h);
}
__device__ __forceinline__ h2 u2h2(unsigned int v) { return __builtin_bit_cast(h2, v); }
__device__ __forceinline__ unsigned int h22u(h2 v) { return __builtin_bit_cast(unsigned int, v); }
__device__ __forceinline__ float ssp(float v) {  // shifted softplus
  return fmaxf(v, 0.f) + __logf(1.f + __expf(-fabsf(v))) - LOG2F_;
}

// ================= merged setup: pair / prep / table / zero =================
__global__ __launch_bounds__(256, 2) void setup_kernel(
    const float* __restrict__ pos, int2* __restrict__ pairb,
    const float* __restrict__ lin1, const float* __restrict__ lin2,
    const float* __restrict__ lin, unsigned short* __restrict__ frag,
    const float* __restrict__ w1_, const float* __restrict__ b1_,
    const float* __restrict__ w2_, const float* __restrict__ b2_,
    unsigned short* __restrict__ tab16_, float* __restrict__ sch) {
  __shared__ unsigned short w1f[8192];
  __shared__ unsigned short w2f[16384];
  __shared__ unsigned short t1s[4][16 * 136];
  const int bid = blockIdx.x, tid = threadIdx.x;

  if (bid < 2000) {                          // ---- per-pair {byte off, frac fp16x2}
    int p = bid * 256 + tid;
    int i = p >> 4, k = (p & 15) + 1;
    bool valid = (i % NPGC) + k < NPGC;
    int j = i + k; if (j >= NATOMS) j = NATOMS - 1;
    float dx = pos[3 * i] - pos[3 * j];
    float dy = pos[3 * i + 1] - pos[3 * j + 1];
    float dz = pos[3 * i + 2] - pos[3 * j + 2];
    float d = sqrtf(dx * dx + dy * dy + dz * dz);
    int2 pv;
    if (valid) {
      float uu = fminf(d * DSCALE, 2044.0f);
      int idx = (int)uu;
      _Float16 fh = (_Float16)(uu - (float)idx);
      h2 fp = {fh, fh};
      pv.x = idx * 512;                      // row stride 512 B
      pv.y = (int)h22u(fp);
    } else {
      pv.x = 2046 * 512;                     // zero row
      pv.y = 0;
    }
    pairb[p] = pv;
    return;
  }
  if (bid < 2018) {                          // ---- weight swizzle to B-frag layout
    int mat = bid - 2000;                    // 0..5 lin1, 6..11 lin2, 12..17 lin
    const float* w = mat < 6 ? lin1 + (size_t)mat * 16384
                   : mat < 12 ? lin2 + (size_t)(mat - 6) * 16384
                   : lin + (size_t)(mat - 12) * 16384;
    unsigned short* f = frag + (size_t)mat * 16384;
    for (int q = 0; q < 64; ++q) {
      int e = q * 256 + tid;
      int j = e & 7, lane = (e >> 3) & 63, tt = e >> 9;
      int n = tt >> 2, ks = tt & 3;
      int krow = ks * 32 + ((lane >> 4) << 3) + j;
      int col = (n << 4) + (lane & 15);
      f[e] = f2h(w[krow * 128 + col]);
    }
    return;
  }
  if (bid < 2210) {                          // ---- filter tables (MFMA, fp16 out)
    int t = bid - 2018;
    const int layer = t >> 5, bx = t & 31;
    const float* w1 = w1_ + (size_t)layer * 50 * 128;
    const float* b1 = b1_ + (size_t)layer * 128;
    const float* w2 = w2_ + (size_t)layer * 128 * 128;
    const float* b2 = b2_ + (size_t)layer * 128;
    unsigned short* tab16 = tab16_ + (size_t)layer * TROWS * 256;

    for (int q = 0; q < 32; ++q) {
      int e = q * 256 + tid;
      int j = e & 7, lane = (e >> 3) & 63, tt = e >> 9;   // tt = n*2+ks
      int n = tt >> 1, ks = tt & 1;
      int krow = ks * 32 + ((lane >> 4) << 3) + j;
      int col = (n << 4) + (lane & 15);
      w1f[e] = f2h((krow < 50) ? w1[krow * 128 + col] : 0.f);
    }
    for (int q = 0; q < 64; ++q) {
      int e = q * 256 + tid;
      int j = e & 7, lane = (e >> 3) & 63, tt = e >> 9;   // tt = n*4+ks
      int n = tt >> 2, ks = tt & 3;
      int krow = ks * 32 + ((lane >> 4) << 3) + j;
      int col = (n << 4) + (lane & 15);
      w2f[e] = f2h(w2[krow * 128 + col]);
    }
    __syncthreads();

    const int lane = tid & 63, wv = tid >> 6;
    const int r = lane & 15, kg = lane >> 4;
    const int tile = bx * 4 + wv;            // 0..127
    float b1v[8], b2v[8];
    #pragma unroll
    for (int n = 0; n < 8; ++n) { b1v[n] = b1[(n << 4) + r]; b2v[n] = b2[(n << 4) + r]; }
    unsigned short* t1p = t1s[wv];

    const int p0 = tile << 4;
    const float step = 5.0f / 49.0f;
    const float coeff = -0.5f / (step * step);
    const float d = (float)(p0 + r) * (1.0f / DSCALE);
    f16x8 a0, a1;
    #pragma unroll
    for (int j = 0; j < 8; ++j) {            // rbf(d) A-fragment, K padded to 64
      int g0 = (kg << 3) + j, g1 = g0 + 32;
      float t0 = d - step * g0, t1 = d - step * g1;
      a0[j] = (_Float16)((g0 < 50) ? __expf(coeff * t0 * t0) : 0.f);
      a1[j] = (_Float16)((g1 < 50) ? __expf(coeff * t1 * t1) : 0.f);
    }
    #pragma unroll
    for (int n = 0; n < 8; ++n) {            // GEMM1 (K=64) + ssp
      const f16x8 bA = *(const f16x8*)&w1f[(((n << 1)) * 64 + lane) << 3];
      const f16x8 bB = *(const f16x8*)&w1f[(((n << 1) | 1) * 64 + lane) << 3];
      f32x4 acc = {0.f, 0.f, 0.f, 0.f};
      acc = MFMA16H(a0, bA, acc);
      acc = MFMA16H(a1, bB, acc);
      #pragma unroll
      for (int j = 0; j < 4; ++j)
        t1p[((kg << 2) + j) * 136 + (n << 4) + r] = f2h(ssp(acc[j] + b1v[n]));
    }
    f16x8 a2[4];
    #pragma unroll
    for (int ks = 0; ks < 4; ++ks)
      a2[ks] = *(const f16x8*)&t1p[r * 136 + (ks << 5) + (kg << 3)];
    float cv[4];
    #pragma unroll
    for (int j = 0; j < 4; ++j) {
      float dj = (float)(p0 + (kg << 2) + j) * (1.0f / DSCALE);
      cv[j] = 0.5f * (__cosf(dj * 0.62831853071795865f) + 1.0f);
    }
    #pragma unroll
    for (int n = 0; n < 8; ++n) {            // GEMM2 (K=128) + *C -> interleaved table
      f32x4 acc = {0.f, 0.f, 0.f, 0.f};
      #pragma unroll
      for (int ks = 0; ks < 4; ++ks)
        acc = MFMA16H(a2[ks], *(const f16x8*)&w2f[(((n << 2) | ks) * 64 + lane) << 3], acc);
      #pragma unroll
      for (int j = 0; j < 4; ++j) {
        int row = p0 + (kg << 2) + j;
        int ch = (n << 4) + r;
        float val = (acc[j] + b2v[n]) * cv[j];
        if (row >= TROWS - 2) val = 0.f;     // zero rows for invalid pairs
        unsigned short hv = f2h(val);
        size_t rb = (size_t)row * 256 + ((ch >> 1) << 2) + (ch & 1);
        tab16[rb] = hv;                      // lo slot of row
        if (row > 0) tab16[rb - 256 + 2] = hv;  // hi slot of row-1
      }
    }
    return;
  }
  if (tid < 32) sch[tid] = 0.f;              // ---- zero graph sums
}

// ============ x0 = emb[z] @ lin1_0 (fp16) ; also writes h0 = emb[z] ============
__global__ __launch_bounds__(256, 2) void xgemm_kernel(
    const int* __restrict__ z, const float* __restrict__ emb,
    const unsigned short* __restrict__ frag,
    float* __restrict__ h, unsigned short* __restrict__ x) {
  const int tid = threadIdx.x, lane = tid & 63, wv = tid >> 6;
  const int wr = wv >> 1, wn = wv & 1;
  const int r = lane & 15, kg = lane >> 4;
  const int p0 = blockIdx.x * 32 + wr * 16;
  const float* hp = emb + (size_t)z[p0 + r] * 128 + (kg << 3);
  f16x8 a[4];
  #pragma unroll
  for (int ks = 0; ks < 4; ++ks) {
    float4 f0 = *(const float4*)(hp + (ks << 5));
    float4 f1 = *(const float4*)(hp + (ks << 5) + 4);
    f16x8 av;
    av[0] = (_Float16)f0.x; av[1] = (_Float16)f0.y;
    av[2] = (_Float16)f0.z; av[3] = (_Float16)f0.w;
    av[4] = (_Float16)f1.x; av[5] = (_Float16)f1.y;
    av[6] = (_Float16)f1.z; av[7] = (_Float16)f1.w;
    a[ks] = av;
    if (wn == 0) {                           // write h0 once
      *(float4*)&h[(size_t)(p0 + r) * 128 + (ks << 5) + (kg << 3)] = f0;
      *(float4*)&h[(size_t)(p0 + r) * 128 + (ks << 5) + (kg << 3) + 4] = f1;
    }
  }
  #pragma unroll
  for (int n = 0; n < 4; ++n) {
    int nn = (wn << 2) + n;
    f32x4 acc = {0.f, 0.f, 0.f, 0.f};
    #pragma unroll
    for (int ks = 0; ks < 4; ++ks)
      acc = MFMA16H(a[ks], *(const f16x8*)&frag[((((nn << 2) | ks) * 64 + lane) << 3)], acc);
    #pragma unroll
    for (int j = 0; j < 4; ++j)
      x[(size_t)(p0 + (kg << 2) + j) * 128 + (nn << 4) + r] = f2h(acc[j]);
  }
}

// ====== fused CFConv layer: pipelined agg + 3 MFMA GEMMs, 32 atoms/block ======
template <int LAST>
__global__ __launch_bounds__(256, 4) void cfconv_kernel(
    const unsigned short* __restrict__ tab16,
    const int2* __restrict__ pairb,
    const unsigned short* __restrict__ x,
    const unsigned short* __restrict__ w2f, const float* __restrict__ b2,
    const unsigned short* __restrict__ wlf, const float* __restrict__ bl,
    const unsigned short* __restrict__ w1nf,
    float* __restrict__ h, unsigned short* __restrict__ xout) {
  __shared__ unsigned short xs[64 * 128];    // 16 KB: x rows [base-16, base+48)
  __shared__ int2 ps[48 * 16];               // 6 KB: pair rows [base-16, base+32)
  __shared__ unsigned short t1s[32 * 136];   // 8.7 KB
  const int tid = threadIdx.x, lane = tid & 63, wv = tid >> 6;
  const int base = blockIdx.x * 32;
  #pragma unroll
  for (int q = 0; q < 4; ++q) {              // stage x halo
    int e = q * 256 + tid;
    int rr = e >> 4, c8 = e & 15;
    int src = base - 16 + rr;
    src = src < 0 ? 0 : (src >= NATOMS ? NATOMS - 1 : src);
    *(uint4*)&xs[rr * 128 + (c8 << 3)] = *(const uint4*)&x[(size_t)src * 128 + (c8 << 3)];
  }
  #pragma unroll
  for (int q = 0; q < 3; ++q) {              // stage pair rows
    int e = q * 256 + tid;
    int rr = e >> 4, kk = e & 15;
    int src = base - 16 + rr;
    src = src < 0 ? 0 : src;
    ps[e] = pairb[(size_t)src * 16 + kk];
  }
  __syncthreads();

  // ---- aggregation: thread = 4 atoms x 4 channels; 8 table loads in flight ----
  const int half = lane >> 5, cgi = lane & 31;
  const int c = cgi << 2;
  const char* tbc = (const char*)tab16 + (c << 2);
  if (base > 0) {                            // fast path: no left-boundary guards
    for (int m = 0; m < 4; ++m) {
      const int ia = (wv << 3) + (half << 2) + m;
      const int li = ia + 16;
      const unsigned short* xrow = xs + li * 128 + c;
      const int2* psr = ps + li * 16;
      h2 acc01 = {(_Float16)0.f, (_Float16)0.f};
      h2 acc23 = acc01;
      #pragma unroll
      for (int chnk = 0; chnk < 2; ++chnk) { // RIGHT neighbors, k = chnk*8+1..+8
        int2 pr[8];
        #pragma unroll
        for (int q = 0; q < 8; ++q) pr[q] = psr[chnk * 8 + q];
        uint4 t[8]; uint2 xv[8];
        #pragma unroll
        for (int q = 0; q < 8; ++q) {
          t[q] = *(const uint4*)(tbc + (unsigned)pr[q].x);
          xv[q] = *(const uint2*)(xrow + ((chnk * 8 + q + 1) << 7));
        }
        #pragma unroll
        for (int q = 0; q < 8; ++q) {
          h2 fr = u2h2((unsigned)pr[q].y);
          h2 lo01 = u2h2(t[q].x), hi01 = u2h2(t[q].y);
          h2 lo23 = u2h2(t[q].z), hi23 = u2h2(t[q].w);
          acc01 += (lo01 + fr * (hi01 - lo01)) * u2h2(xv[q].x);
          acc23 += (lo23 + fr * (hi23 - lo23)) * u2h2(xv[q].y);
        }
      }
      #pragma unroll
      for (int chnk = 0; chnk < 2; ++chnk) { // LEFT neighbors (mirror slots)
        int2 pr[8];
        #pragma unroll
        for (int q = 0; q < 8; ++q) {
          int k = chnk * 8 + q + 1;
          pr[q] = ps[(li - k) * 16 + (k - 1)];
        }
        uint4 t[8]; uint2 xv[8];
        #pragma unroll
        for (int q = 0; q < 8; ++q) {
          t[q] = *(const uint4*)(tbc + (unsigned)pr[q].x);
          xv[q] = *(const uint2*)(xrow - ((chnk * 8 + q + 1) << 7));
        }
        #pragma unroll
        for (int q = 0; q < 8; ++q) {
          h2 fr = u2h2((unsigned)pr[q].y);
          h2 lo01 = u2h2(t[q].x), hi01 = u2h2(t[q].y);
          h2 lo23 = u2h2(t[q].z), hi23 = u2h2(t[q].w);
          acc01 += (lo01 + fr * (hi01 - lo01)) * u2h2(xv[q].x);
          acc23 += (lo23 + fr * (hi23 - lo23)) * u2h2(xv[q].y);
        }
      }
      uint2 o = {h22u(acc01), h22u(acc23)};
      *(uint2*)&t1s[ia * 136 + c] = o;
    }
  } else {                                   // block 0: guarded left edges
    for (int m = 0; m < 4; ++m) {
      const int ia = (wv << 3) + (half << 2) + m;
      const int i = base + ia;
      const int li = ia + 16;
      h2 acc01 = {(_Float16)0.f, (_Float16)0.f};
      h2 acc23 = acc01;
      #pragma unroll
      for (int k = 1; k <= 16; ++k) {
        int2 pr = ps[li * 16 + k - 1];
        h2 fr = u2h2((unsigned)pr.y);
        uint4 t = *(const uint4*)(tbc + (unsigned)pr.x);
        uint2 xv = *(const uint2*)&xs[(li + k) * 128 + c];
        h2 lo01 = u2h2(t.x), hi01 = u2h2(t.y), lo23 = u2h2(t.z), hi23 = u2h2(t.w);
        acc01 += (lo01 + fr * (hi01 - lo01)) * u2h2(xv.x);
        acc23 += (lo23 + fr * (hi23 - lo23)) * u2h2(xv.y);
      }
      #pragma unroll
      for (int k = 1; k <= 16; ++k) {
        if (i - k >= 0) {
          int2 pr = ps[(li - k) * 16 + (k - 1)];
          h2 fr = u2h2((unsigned)pr.y);
          uint4 t = *(const uint4*)(tbc + (unsigned)pr.x);
          uint2 xv = *(const uint2*)&xs[(li - k) * 128 + c];
          h2 lo01 = u2h2(t.x), hi01 = u2h2(t.y), lo23 = u2h2(t.z), hi23 = u2h2(t.w);
          acc01 += (lo01 + fr * (hi01 - lo01)) * u2h2(xv.x);
          acc23 += (lo23 + fr * (hi23 - lo23)) * u2h2(xv.y);
        }
      }
      uint2 o = {h22u(acc01), h22u(acc23)};
      *(uint2*)&t1s[ia * 136 + c] = o;
    }
  }
  __syncthreads();

  // ---- GEMM phase: wave (wr,wn) owns 16-row half x 64-col half ----
  const int wr = wv >> 1, wn = wv & 1;
  const int r = lane & 15, kg = lane >> 4;
  const int p0 = base + wr * 16;
  const int p0l = wr * 16;
  float b2v[4], blv[4];
  #pragma unroll
  for (int n = 0; n < 4; ++n) {
    int cc = (((wn << 2) + n) << 4) + r;
    b2v[n] = b2[cc]; blv[n] = bl[cc];
  }
  f16x8 a[4];
  #pragma unroll
  for (int ks = 0; ks < 4; ++ks)
    a[ks] = *(const f16x8*)&t1s[(p0l + r) * 136 + (ks << 5) + (kg << 3)];
  __syncthreads();                           // agg reads done before t1 overwrite
  #pragma unroll
  for (int n = 0; n < 4; ++n) {              // GEMM1: agg@lin2 + b2, ssp -> t1
    int nn = (wn << 2) + n;
    f32x4 acc = {0.f, 0.f, 0.f, 0.f};
    #pragma unroll
    for (int ks = 0; ks < 4; ++ks)
      acc = MFMA16H(a[ks], *(const f16x8*)&w2f[((((nn << 2) | ks) * 64 + lane) << 3)], acc);
    #pragma unroll
    for (int j = 0; j < 4; ++j)
      t1s[(p0l + (kg << 2) + j) * 136 + (nn << 4) + r] = f2h(ssp(acc[j] + b2v[n]));
  }
  __syncthreads();
  f16x8 a2[4];
  #pragma unroll
  for (int ks = 0; ks < 4; ++ks)
    a2[ks] = *(const f16x8*)&t1s[(p0l + r) * 136 + (ks << 5) + (kg << 3)];
  float hn[4][4];
  #pragma unroll
  for (int n = 0; n < 4; ++n) {              // GEMM2: v@lin_w + bl + h -> h
    int nn = (wn << 2) + n;
    f32x4 acc = {0.f, 0.f, 0.f, 0.f};
    #pragma unroll
    for (int ks = 0; ks < 4; ++ks)
      acc = MFMA16H(a2[ks], *(const f16x8*)&wlf[((((nn << 2) | ks) * 64 + lane) << 3)], acc);
    #pragma unroll
    for (int j = 0; j < 4; ++j) {
      size_t off = (size_t)(p0 + (kg << 2) + j) * 128 + (nn << 4) + r;
      float val = h[off] + acc[j] + blv[n];
      h[off] = val;
      hn[n][j] = val;
    }
  }
  if constexpr (!LAST) {                     // GEMM3: x' = h_new @ lin1_next
    __syncthreads();                         // a2 reads done
    #pragma unroll
    for (int n = 0; n < 4; ++n)
      #pragma unroll
      for (int j = 0; j < 4; ++j)
        t1s[(p0l + (kg << 2) + j) * 136 + ((((wn << 2) + n)) << 4) + r] = f2h(hn[n][j]);
    __syncthreads();
    f16x8 a3[4];
    #pragma unroll
    for (int ks = 0; ks < 4; ++ks)
      a3[ks] = *(const f16x8*)&t1s[(p0l + r) * 136 + (ks << 5) + (kg << 3)];
    #pragma unroll
    for (int n = 0; n < 4; ++n) {
      int nn = (wn << 2) + n;
      f32x4 acc = {0.f, 0.f, 0.f, 0.f};
      #pragma unroll
      for (int ks = 0; ks < 4; ++ks)
        acc = MFMA16H(a3[ks], *(const f16x8*)&w1nf[((((nn << 2) | ks) * 64 + lane) << 3)], acc);
      #pragma unroll
      for (int j = 0; j < 4; ++j)
        xout[(size_t)(p0 + (kg << 2) + j) * 128 + (nn << 4) + r] = f2h(acc[j]);
    }
  }
}

// ---------------- output head ----------------
__global__ __launch_bounds__(256, 4) void head_atoms(const float* __restrict__ h,
    const float* __restrict__ o1w, const float* __restrict__ o1b,
    const float* __restrict__ o2w, const float* __restrict__ o2b,
    float* __restrict__ sch) {
  __shared__ float o1wT[64 * 132];
  __shared__ float hs[4][128];
  __shared__ float schloc[2];
  const int tid = threadIdx.x, lane = tid & 63, wv = tid >> 6;
  #pragma unroll
  for (int q = 0; q < 8; ++q) {
    int e4 = q * 256 + tid;
    int k = e4 >> 4, c0 = (e4 & 15) << 2;
    float4 v = ((const float4*)o1w)[e4];
    o1wT[(c0 + 0) * 132 + k] = v.x;
    o1wT[(c0 + 1) * 132 + k] = v.y;
    o1wT[(c0 + 2) * 132 + k] = v.z;
    o1wT[(c0 + 3) * 132 + k] = v.w;
  }
  if (tid < 2) schloc[tid] = 0.f;
  __syncthreads();
  const int base = blockIdx.x * 64;
  const int g0 = base / NPGC;
  const float o1bv = o1b[lane], o2wv = o2w[lane], o2bv = o2b[0];
  for (int m = 0; m < 16; ++m) {
    int i = base + (wv << 4) + m;
    __syncthreads();
    if (lane < 32) ((float4*)hs[wv])[lane] = ((const float4*)h)[(size_t)i * 32 + lane];
    __syncthreads();
    float4 acc = {0.f, 0.f, 0.f, 0.f};
    #pragma unroll
    for (int k4 = 0; k4 < 32; ++k4) {
      float4 wv4 = *(const float4*)&o1wT[lane * 132 + (k4 << 2)];
      float4 hb = ((const float4*)hs[wv])[k4];
      acc.x = fmaf(hb.x, wv4.x, acc.x);
      acc.y = fmaf(hb.y, wv4.y, acc.y);
      acc.z = fmaf(hb.z, wv4.z, acc.z);
      acc.w = fmaf(hb.w, wv4.w, acc.w);
    }
    float pa = ssp(acc.x + acc.y + acc.z + acc.w + o1bv) * o2wv;
    #pragma unroll
    for (int off = 32; off; off >>= 1) pa += __shfl_down(pa, off);
    if (lane == 0) atomicAdd(&schloc[(i / NPGC) - g0], pa + o2bv);
  }
  __syncthreads();
  if (tid < 2 && g0 + tid < 32) atomicAdd(&sch[g0 + tid], schloc[tid]);
}

__global__ void head_final(const float* __restrict__ sch,
    const float* __restrict__ h1w, const float* __restrict__ h1b,
    const float* __restrict__ h2w, const float* __restrict__ h2b,
    float* __restrict__ out) {
  int g = threadIdx.x;
  if (g < 32) {
    float s = sch[g], acc = h2b[0];
    for (int c = 0; c < 64; ++c) {
      float t = fmaf(s, h1w[c], h1b[c]);
      acc = fmaf(fmaxf(t, 0.f), h2w[c], acc);
    }
    out[g] = acc;
  }
}

extern "C" void kernel_launch(void* const* d_in, const int* in_sizes, int n_in,
                              void* d_out, int out_size, void* d_ws, size_t ws_size,
                              hipStream_t stream) {
  const int*   z       = (const int*)d_in[0];
  const float* pos     = (const float*)d_in[1];
  const float* emb     = (const float*)d_in[5];
  const float* mlp_w1  = (const float*)d_in[6];
  const float* mlp_b1  = (const float*)d_in[7];
  const float* mlp_w2  = (const float*)d_in[8];
  const float* mlp_b2  = (const float*)d_in[9];
  const float* lin1_w  = (const float*)d_in[10];
  const float* lin2_w  = (const float*)d_in[11];
  const float* lin2_b  = (const float*)d_in[12];
  const float* lin_w   = (const float*)d_in[13];
  const float* lin_b   = (const float*)d_in[14];
  const float* out1_w  = (const float*)d_in[15];
  const float* out1_b  = (const float*)d_in[16];
  const float* out2_w  = (const float*)d_in[17];
  const float* out2_b  = (const float*)d_in[18];
  const float* head1_w = (const float*)d_in[19];
  const float* head1_b = (const float*)d_in[20];
  const float* head2_w = (const float*)d_in[21];
  const float* head2_b = (const float*)d_in[22];
  float* outp = (float*)d_out;

  char* ws = (char*)d_ws;
  const size_t SZ_NODE = (size_t)NATOMS * 128 * 4;  // 16.384 MB
  float* h    = (float*)ws;                   ws += SZ_NODE;
  unsigned short* xA   = (unsigned short*)ws; ws += SZ_NODE / 2;   // fp16
  unsigned short* xB   = (unsigned short*)ws; ws += SZ_NODE / 2;   // fp16
  int2* pairb = (int2*)ws;                    ws += (size_t)PSLOT * 8;
  unsigned short* tab16 = (unsigned short*)ws; ws += (size_t)6 * TROWS * 512;
  unsigned short* frag = (unsigned short*)ws; ws += (size_t)18 * 16384 * 2;
  float* sch  = (float*)ws;                   ws += 256;
  if ((size_t)(ws - (char*)d_ws) > ws_size) return;

  const unsigned short* f_lin1 = frag;
  const unsigned short* f_lin2 = frag + (size_t)6 * 16384;
  const unsigned short* f_lin  = frag + (size_t)12 * 16384;

  setup_kernel<<<2211, 256, 0, stream>>>(pos, pairb, lin1_w, lin2_w, lin_w, frag,
                                         mlp_w1, mlp_b1, mlp_w2, mlp_b2, tab16, sch);
  xgemm_kernel<<<NATOMS / 32, 256, 0, stream>>>(z, emb, f_lin1, h, xA);

  for (int l = 0; l < 6; ++l) {
    unsigned short* xin  = (l & 1) ? xB : xA;
    unsigned short* xo   = (l & 1) ? xA : xB;
    if (l < 5)
      cfconv_kernel<0><<<NATOMS / 32, 256, 0, stream>>>(
          tab16 + (size_t)l * TROWS * 256, pairb, xin,
          f_lin2 + (size_t)l * 16384, lin2_b + (size_t)l * 128,
          f_lin + (size_t)l * 16384, lin_b + (size_t)l * 128,
          f_lin1 + (size_t)(l + 1) * 16384, h, xo);
    else
      cfconv_kernel<1><<<NATOMS / 32, 256, 0, stream>>>(
          tab16 + (size_t)l * TROWS * 256, pairb, xin,
          f_lin2 + (size_t)l * 16384, lin2_b + (size_t)l * 128,
          f_lin + (size_t)l * 16384, lin_b + (size_t)l * 128,
          f_lin1, h, xo);
  }
  head_atoms<<<NATOMS / 64, 256, 0, stream>>>(h, out1_w, out1_b, out2_w, out2_b, sch);
  head_final<<<1, 64, 0, stream>>>(sch, head1_w, head1_b, head2_w, head2_b, outp);
}